// Round 12
// baseline (184.141 us; speedup 1.0000x reference)
//
#include <hip/hip_runtime.h>
#include <hip/hip_bf16.h>

#define NC 3000   // num cates
#define NP 3072   // padded
#define CAP 64    // ELL slots per row (max degree ~52 at p=0.01; binom tail past 64 ~ 0)
#define HD 64
#define NG 4
#define LQ 50
#define NB 256
#define NQ4 750   // float4 words per adj row = NC/4

// Fully-unrolled 64-slot shfl-broadcast gather. A row in (vreg,creg) registers, slot = lane;
// slots >= d hold (0,0) so extra terms are exact zeros (z[0] line is L1-hot). 8 independent
// accumulator chains let the compiler put all 64 loads in flight -> ONE memory round-trip
// (vs 4 serial batches in the old GATHER8). VGPRs are free: grid-limited 3 waves/SIMD.
#define GATHER64(accout, vreg, creg, zin)                                  \
  {                                                                        \
    float _a[8] = {0.f, 0.f, 0.f, 0.f, 0.f, 0.f, 0.f, 0.f};               \
    _Pragma("unroll")                                                      \
    for (int _e = 0; _e < CAP; ++_e) {                                     \
      float _v = __shfl(vreg, _e);                                         \
      int _c = __shfl(creg, _e);                                           \
      _a[_e & 7] += _v * zin[_c * HD + lane];                              \
    }                                                                      \
    accout = ((_a[0] + _a[1]) + (_a[2] + _a[3]))                           \
           + ((_a[4] + _a[5]) + (_a[6] + _a[7]));                          \
  }

// ---- K1: pack adj -> ELL colb + deg (float4 + 4-ballot compaction), qkv layer 1, zero Sb.
__global__ __launch_bounds__(256) void k_pack_qkv(const float* __restrict__ adj,
    const float* __restrict__ emb, const float* __restrict__ Wq, const float* __restrict__ Wk,
    const float* __restrict__ Wv, int* __restrict__ colb, int* __restrict__ deg,
    float* __restrict__ qf, float* __restrict__ kf, float* __restrict__ vf,
    float* __restrict__ Sb) {
  const int tid = threadIdx.x, lane = tid & 63;
  const int row = blockIdx.x * 4 + (tid >> 6);
  if (blockIdx.x == 0) {           // fold in Sb zeroing (used only by K9, 8 dispatches later)
    if (tid < NG * HD) Sb[tid] = 0.f;
    if (tid == 0) Sb[NG * HD] = 0.f;
  }
  if (row < NC) {
    const float4* arow = reinterpret_cast<const float4*>(adj + (size_t)row * NC);  // 12000B: 16B-aligned
    const unsigned long long mlane = (1ull << lane) - 1ull;
    int base = 0;   // wave-uniform running edge count
#pragma unroll 3
    for (int g = 0; g < 12; ++g) {
      int idx = g * 64 + lane;     // float4 index; valid < NQ4
      float4 a4 = (idx < NQ4) ? arow[idx] : make_float4(0.f, 0.f, 0.f, 0.f);
      unsigned long long b0 = __ballot(a4.x != 0.f);
      unsigned long long b1 = __ballot(a4.y != 0.f);
      unsigned long long b2 = __ballot(a4.z != 0.f);
      unsigned long long b3 = __ballot(a4.w != 0.f);
      if (a4.x != 0.f) { int s = base + __popcll(b0 & mlane); if (s < CAP) colb[row * CAP + s] = 4 * idx + 0; }
      base += __popcll(b0);
      if (a4.y != 0.f) { int s = base + __popcll(b1 & mlane); if (s < CAP) colb[row * CAP + s] = 4 * idx + 1; }
      base += __popcll(b1);
      if (a4.z != 0.f) { int s = base + __popcll(b2 & mlane); if (s < CAP) colb[row * CAP + s] = 4 * idx + 2; }
      base += __popcll(b2);
      if (a4.w != 0.f) { int s = base + __popcll(b3 & mlane); if (s < CAP) colb[row * CAP + s] = 4 * idx + 3; }
      base += __popcll(b3);
    }
    int d = (base < CAP) ? base : CAP;
    if (lane == 0) deg[row] = d;
    if (lane >= d) colb[row * CAP + lane] = 0;   // zero-fill tail (val tail will be 0)
    // qkv: lane = output col; h row broadcast via shfl
    float hreg = emb[row * HD + lane];
    float aq = 0.f, ak = 0.f, av = 0.f;
#pragma unroll 16
    for (int f = 0; f < HD; ++f) {
      float hv = __shfl(hreg, f);
      aq += hv * Wq[f * HD + lane];
      ak += hv * Wk[f * HD + lane];
      av += hv * Wv[f * HD + lane];
    }
    qf[row * HD + lane] = aq;
    kf[row * HD + lane] = ak;
    vf[row * HD + lane] = av;
  } else {
    if (lane == 0) deg[row] = 0;
    colb[row * CAP + lane] = 0;
    qf[row * HD + lane] = 0.f;
    kf[row * HD + lane] = 0.f;
    vf[row * HD + lane] = 0.f;
  }
}

// ---- K2/K6: edge-wise scores + softmax + hop1. Wave per row; lane = edge slot.
// (per-lane float4-streamed k-row dot: measured faster than coalesced+butterfly — issue-bound)
__global__ __launch_bounds__(256) void k_score_hop(const float* __restrict__ qf,
    const float* __restrict__ kf, const int* __restrict__ colb, const int* __restrict__ deg,
    float* __restrict__ val, const float* __restrict__ vf, float* __restrict__ zA) {
  const int tid = threadIdx.x, lane = tid & 63;
  const int row = blockIdx.x * 4 + (tid >> 6);
  const int d = deg[row];
  const int creg = colb[row * CAP + lane];
  const float qreg = qf[row * HD + lane];   // lane f holds q[row][f]
  // lane e: s_e = q_row . k_{c_e}  (fp32, float4-streamed k row)
  float acc = 0.f;
  const float4* kr = reinterpret_cast<const float4*>(kf + creg * HD);
#pragma unroll
  for (int i = 0; i < 16; ++i) {
    float4 k4 = kr[i];
    acc += __shfl(qreg, 4 * i + 0) * k4.x;
    acc += __shfl(qreg, 4 * i + 1) * k4.y;
    acc += __shfl(qreg, 4 * i + 2) * k4.z;
    acc += __shfl(qreg, 4 * i + 3) * k4.w;
  }
  float e = (lane < d) ? __expf(acc * 0.125f) : 0.f;  // |s| O(1): no max-sub needed in fp32
  float s = e;
#pragma unroll
  for (int off = 1; off < 64; off <<= 1) s += __shfl_xor(s, off);
  float vreg = (s > 0.f) ? e / s : 0.f;               // normalized A row, slot = lane; 0 for lane>=d
  val[row * CAP + lane] = vreg;
  // hop1 (zin = vf): one-round-trip gather
  float hacc;
  GATHER64(hacc, vreg, creg, vf);
  zA[row * HD + lane] = 0.85f * hacc + 0.15f * vf[row * HD + lane];
}

// ---- K3/K4/K7/K8: plain sparse hop. Wave per row; A row in registers, 64 loads in flight.
__global__ __launch_bounds__(256) void k_hop(const float* __restrict__ val,
    const int* __restrict__ colb, const float* __restrict__ zin,
    const float* __restrict__ vf, float* __restrict__ zout) {
  const int lane = threadIdx.x & 63;
  const int row = blockIdx.x * 4 + (threadIdx.x >> 6);
  const float vreg = val[row * CAP + lane];
  const int creg = colb[row * CAP + lane];
  float acc;
  GATHER64(acc, vreg, creg, zin);
  zout[row * HD + lane] = 0.85f * acc + 0.15f * vf[row * HD + lane];
}

// ---- K5: hop4 + residual (h = emb + z) + qkv layer 2. Row-local via shfl.
__global__ __launch_bounds__(256) void k_hop_res_qkv(const float* __restrict__ val,
    const int* __restrict__ colb, const float* __restrict__ zin,
    const float* __restrict__ vf, const float* __restrict__ emb, float* __restrict__ hf,
    const float* __restrict__ Wq, const float* __restrict__ Wk, const float* __restrict__ Wv,
    float* __restrict__ qf, float* __restrict__ kf, float* __restrict__ vf2) {
  const int lane = threadIdx.x & 63;
  const int row = blockIdx.x * 4 + (threadIdx.x >> 6);
  const float vreg = val[row * CAP + lane];
  const int creg = colb[row * CAP + lane];
  float acc;
  GATHER64(acc, vreg, creg, zin);
  float z = 0.85f * acc + 0.15f * vf[row * HD + lane];
  float h = ((row < NC) ? emb[row * HD + lane] : 0.f) + z;
  hf[row * HD + lane] = h;
  float aq = 0.f, ak = 0.f, av = 0.f;
#pragma unroll 16
  for (int f = 0; f < HD; ++f) {
    float hv = __shfl(h, f);
    aq += hv * Wq[f * HD + lane];
    ak += hv * Wk[f * HD + lane];
    av += hv * Wv[f * HD + lane];
  }
  qf[row * HD + lane] = aq;
  kf[row * HD + lane] = ak;
  vf2[row * HD + lane] = av;
}

// ---- K9: hop4' + residual + cluster softmax + S/Wsum partials (LDS pre-reduced).
__global__ __launch_bounds__(1024) void k_hop_res_tail(const float* __restrict__ val,
    const int* __restrict__ colb, const float* __restrict__ zin,
    const float* __restrict__ vf, float* __restrict__ hf, const float* __restrict__ Wg,
    const float* __restrict__ bg, const float* __restrict__ Wp, float* __restrict__ s2,
    float* __restrict__ Sb) {
  __shared__ float Sl[NG * HD];
  __shared__ float Wl[16];
  const int tid = threadIdx.x, lane = tid & 63, wave = tid >> 6;
  const int row = blockIdx.x * 16 + wave;
  if (tid < NG * HD) Sl[tid] = 0.f;
  if (tid < 16) Wl[tid] = 0.f;
  __syncthreads();
  const float vreg = val[row * CAP + lane];
  const int creg = colb[row * CAP + lane];
  float acc;
  GATHER64(acc, vreg, creg, zin);
  float z = 0.85f * acc + 0.15f * vf[row * HD + lane];
  float h = hf[row * HD + lane] + z;
  hf[row * HD + lane] = h;
  if (row < NC) {
    float4 wg = *reinterpret_cast<const float4*>(Wg + lane * NG);
    float a0 = h * wg.x, a1 = h * wg.y, a2 = h * wg.z, a3 = h * wg.w;
#pragma unroll
    for (int off = 1; off < 64; off <<= 1) {
      a0 += __shfl_xor(a0, off); a1 += __shfl_xor(a1, off);
      a2 += __shfl_xor(a2, off); a3 += __shfl_xor(a3, off);
    }
    float lg0 = a0 + bg[0], lg1 = a1 + bg[1], lg2 = a2 + bg[2], lg3 = a3 + bg[3];
    float mx = fmaxf(fmaxf(lg0, lg1), fmaxf(lg2, lg3));
    float e0 = __expf(lg0 - mx), e1 = __expf(lg1 - mx), e2 = __expf(lg2 - mx), e3 = __expf(lg3 - mx);
    float inv = 1.f / (e0 + e1 + e2 + e3);
    float p0 = e0 * inv, p1 = e1 * inv, p2 = e2 * inv, p3 = e3 * inv;
    if (lane == 0) s2[row] = p0 * p0 + p1 * p1 + p2 * p2 + p3 * p3;
    float w = Wp[row];
    atomicAdd(&Sl[0 * HD + lane], p0 * w * h);
    atomicAdd(&Sl[1 * HD + lane], p1 * w * h);
    atomicAdd(&Sl[2 * HD + lane], p2 * w * h);
    atomicAdd(&Sl[3 * HD + lane], p3 * w * h);
    if (lane == 0) Wl[wave] = w;
  }
  __syncthreads();
  if (tid < NG * HD) atomicAdd(&Sb[tid], Sl[tid]);
  if (tid == 0) {
    float ws = 0.f;
#pragma unroll
    for (int i = 0; i < 16; ++i) ws += Wl[i];
    atomicAdd(&Sb[NG * HD], ws);
  }
}

// ---- K10: per-user closed-form BN + pool. 4 waves split the L-gather chain.
__global__ __launch_bounds__(256) void k_user(const int* __restrict__ cate, const float* __restrict__ hf,
    const float* __restrict__ s2, const float* __restrict__ Sb,
    const float* __restrict__ gamma, const float* __restrict__ beta, const float* __restrict__ bp,
    float* __restrict__ out) {
  const int b = blockIdx.x;
  const int tid = threadIdx.x, lane = tid & 63, wave = tid >> 6;
  __shared__ int cs[LQ];
  __shared__ float red[8][HD];
  if (tid < LQ) cs[tid] = cate[b * LQ + tid];
  __syncthreads();
  float msum = 0.f, qsum = 0.f;
#pragma unroll 4
  for (int l = wave; l < LQ; l += 4) {
    int c = cs[l];
    if (c != 0) {
      float gv = hf[c * HD + lane];
      msum += gv;
      qsum += s2[c] * gv * gv;
    }
  }
  red[wave][lane] = msum;
  red[4 + wave][lane] = qsum;
  __syncthreads();
  if (wave == 0) {
    msum = red[0][lane] + red[1][lane] + red[2][lane] + red[3][lane];
    qsum = red[4][lane] + red[5][lane] + red[6][lane] + red[7][lane];
    const float cntf = 1.f / (NG * LQ);
    float mean = msum * cntf;
    float var = fmaxf(qsum * cntf - mean * mean, 0.f);
    float inv = rsqrtf(var + 1e-5f);
    float gam = gamma[lane], bet = beta[lane], bpv = bp[0];
    float wsum = Sb[NG * HD];
#pragma unroll
    for (int g = 0; g < NG; ++g)
      out[b * (NG * HD) + g * HD + lane] = inv * gam * (Sb[g * HD + lane] - mean * wsum) + bet * wsum + bpv;
  }
}

extern "C" void kernel_launch(void* const* d_in, const int* in_sizes, int n_in,
                              void* d_out, int out_size, void* d_ws, size_t ws_size,
                              hipStream_t stream) {
  const int* cate = (const int*)d_in[0];
  const float* adj = (const float*)d_in[1];
  const float* emb = (const float*)d_in[2];
  const float* Wq = (const float*)d_in[3];
  const float* Wk = (const float*)d_in[4];
  const float* Wv = (const float*)d_in[5];
  const float* Wg = (const float*)d_in[6];
  const float* bg = (const float*)d_in[7];
  const float* Wp = (const float*)d_in[8];
  const float* bp = (const float*)d_in[9];
  const float* gamma = (const float*)d_in[10];
  const float* beta = (const float*)d_in[11];
  float* out = (float*)d_out;

  char* p = (char*)d_ws;
  auto carve = [&](size_t bytes) { char* r = p; p += (bytes + 255) & ~(size_t)255; return r; };
  float* hf = (float*)carve((size_t)NP * HD * 4);
  float* qf = (float*)carve((size_t)NP * HD * 4);
  float* kf = (float*)carve((size_t)NP * HD * 4);
  float* vf = (float*)carve((size_t)NP * HD * 4);
  float* vf2 = (float*)carve((size_t)NP * HD * 4);
  float* zA = (float*)carve((size_t)NP * HD * 4);
  float* zB = (float*)carve((size_t)NP * HD * 4);
  float* val = (float*)carve((size_t)NP * CAP * 4);
  int* colb = (int*)carve((size_t)NP * CAP * 4);
  int* deg  = (int*)carve((size_t)NP * 4);
  float* s2 = (float*)carve((size_t)NP * 4);
  float* Sb = (float*)carve((size_t)(NG * HD + 1) * 4);

  // layer 1
  k_pack_qkv<<<NP / 4, 256, 0, stream>>>(adj, emb, Wq, Wk, Wv, colb, deg, qf, kf, vf, Sb);
  k_score_hop<<<NP / 4, 256, 0, stream>>>(qf, kf, colb, deg, val, vf, zA);
  k_hop<<<NP / 4, 256, 0, stream>>>(val, colb, zA, vf, zB);
  k_hop<<<NP / 4, 256, 0, stream>>>(val, colb, zB, vf, zA);
  k_hop_res_qkv<<<NP / 4, 256, 0, stream>>>(val, colb, zA, vf, emb, hf,
                                            Wq + HD * HD, Wk + HD * HD, Wv + HD * HD, qf, kf, vf2);
  // layer 2
  k_score_hop<<<NP / 4, 256, 0, stream>>>(qf, kf, colb, deg, val, vf2, zA);
  k_hop<<<NP / 4, 256, 0, stream>>>(val, colb, zA, vf2, zB);
  k_hop<<<NP / 4, 256, 0, stream>>>(val, colb, zB, vf2, zA);
  k_hop_res_tail<<<NP / 16, 1024, 0, stream>>>(val, colb, zA, vf2, hf, Wg, bg, Wp, s2, Sb);
  k_user<<<NB, 256, 0, stream>>>(cate, hf, s2, Sb, gamma, beta, bp, out);
}

// Round 13
// 177.812 us; speedup vs baseline: 1.0356x; 1.0356x over previous
//
#include <hip/hip_runtime.h>
#include <hip/hip_bf16.h>

#define NC 3000   // num cates
#define NP 3072   // padded
#define CAP 64    // ELL slots per row (max degree ~52 at p=0.01; binom tail past 64 ~ 0)
#define HD 64
#define NG 4
#define LQ 50
#define NB 256
#define NQ4 750   // float4 words per adj row = NC/4

// 8-deep unrolled shfl-broadcast gather: A row lives in (vreg,creg) registers, slot = lane.
// Slots >= d hold (0, 0) so rounding d up to 8 adds exact-zero terms. dro <= 64 always.
#define GATHER8(acc, vreg, creg, zin, d)                                   \
  {                                                                        \
    int dro = ((d) + 7) & ~7;                                              \
    for (int e = 0; e < dro; e += 8) {                                     \
      float v0 = __shfl(vreg, e + 0), v1 = __shfl(vreg, e + 1);            \
      float v2 = __shfl(vreg, e + 2), v3 = __shfl(vreg, e + 3);            \
      float v4 = __shfl(vreg, e + 4), v5 = __shfl(vreg, e + 5);            \
      float v6 = __shfl(vreg, e + 6), v7 = __shfl(vreg, e + 7);            \
      int c0 = __shfl(creg, e + 0), c1 = __shfl(creg, e + 1);              \
      int c2 = __shfl(creg, e + 2), c3 = __shfl(creg, e + 3);              \
      int c4 = __shfl(creg, e + 4), c5 = __shfl(creg, e + 5);              \
      int c6 = __shfl(creg, e + 6), c7 = __shfl(creg, e + 7);              \
      float z0 = zin[c0 * HD + lane], z1 = zin[c1 * HD + lane];            \
      float z2 = zin[c2 * HD + lane], z3 = zin[c3 * HD + lane];            \
      float z4 = zin[c4 * HD + lane], z5 = zin[c5 * HD + lane];            \
      float z6 = zin[c6 * HD + lane], z7 = zin[c7 * HD + lane];            \
      acc += v0 * z0 + v1 * z1 + v2 * z2 + v3 * z3;                        \
      acc += v4 * z4 + v5 * z5 + v6 * z6 + v7 * z7;                        \
    }                                                                      \
  }

// ---- K1: pack adj -> ELL colb + deg (float4 + 4-ballot compaction), qkv layer 1, zero Sb.
__global__ __launch_bounds__(256) void k_pack_qkv(const float* __restrict__ adj,
    const float* __restrict__ emb, const float* __restrict__ Wq, const float* __restrict__ Wk,
    const float* __restrict__ Wv, int* __restrict__ colb, int* __restrict__ deg,
    float* __restrict__ qf, float* __restrict__ kf, float* __restrict__ vf,
    float* __restrict__ Sb) {
  const int tid = threadIdx.x, lane = tid & 63;
  const int row = blockIdx.x * 4 + (tid >> 6);
  if (blockIdx.x == 0) {           // fold in Sb zeroing (used only by K9, 8 dispatches later)
    if (tid < NG * HD) Sb[tid] = 0.f;
    if (tid == 0) Sb[NG * HD] = 0.f;
  }
  if (row < NC) {
    const float4* arow = reinterpret_cast<const float4*>(adj + (size_t)row * NC);  // 12000B: 16B-aligned
    const unsigned long long mlane = (1ull << lane) - 1ull;
    int base = 0;   // wave-uniform running edge count
#pragma unroll 3
    for (int g = 0; g < 12; ++g) {
      int idx = g * 64 + lane;     // float4 index; valid < NQ4
      float4 a4 = (idx < NQ4) ? arow[idx] : make_float4(0.f, 0.f, 0.f, 0.f);
      unsigned long long b0 = __ballot(a4.x != 0.f);
      unsigned long long b1 = __ballot(a4.y != 0.f);
      unsigned long long b2 = __ballot(a4.z != 0.f);
      unsigned long long b3 = __ballot(a4.w != 0.f);
      if (a4.x != 0.f) { int s = base + __popcll(b0 & mlane); if (s < CAP) colb[row * CAP + s] = 4 * idx + 0; }
      base += __popcll(b0);
      if (a4.y != 0.f) { int s = base + __popcll(b1 & mlane); if (s < CAP) colb[row * CAP + s] = 4 * idx + 1; }
      base += __popcll(b1);
      if (a4.z != 0.f) { int s = base + __popcll(b2 & mlane); if (s < CAP) colb[row * CAP + s] = 4 * idx + 2; }
      base += __popcll(b2);
      if (a4.w != 0.f) { int s = base + __popcll(b3 & mlane); if (s < CAP) colb[row * CAP + s] = 4 * idx + 3; }
      base += __popcll(b3);
    }
    int d = (base < CAP) ? base : CAP;
    if (lane == 0) deg[row] = d;
    if (lane >= d) colb[row * CAP + lane] = 0;   // zero-fill tail (val tail will be 0)
    // qkv: lane = output col; h row broadcast via shfl
    float hreg = emb[row * HD + lane];
    float aq = 0.f, ak = 0.f, av = 0.f;
#pragma unroll 16
    for (int f = 0; f < HD; ++f) {
      float hv = __shfl(hreg, f);
      aq += hv * Wq[f * HD + lane];
      ak += hv * Wk[f * HD + lane];
      av += hv * Wv[f * HD + lane];
    }
    qf[row * HD + lane] = aq;
    kf[row * HD + lane] = ak;
    vf[row * HD + lane] = av;
  } else {
    if (lane == 0) deg[row] = 0;
    colb[row * CAP + lane] = 0;
    qf[row * HD + lane] = 0.f;
    kf[row * HD + lane] = 0.f;
    vf[row * HD + lane] = 0.f;
  }
}

// ---- K2/K6: edge-wise scores + softmax + hop1. Wave per row; lane = edge slot.
__global__ __launch_bounds__(256) void k_score_hop(const float* __restrict__ qf,
    const float* __restrict__ kf, const int* __restrict__ colb, const int* __restrict__ deg,
    float* __restrict__ val, const float* __restrict__ vf, float* __restrict__ zA) {
  const int tid = threadIdx.x, lane = tid & 63;
  const int row = blockIdx.x * 4 + (tid >> 6);
  const int d = deg[row];
  const int creg = colb[row * CAP + lane];
  const float qreg = qf[row * HD + lane];   // lane f holds q[row][f]
  // lane e: s_e = q_row . k_{c_e}  (fp32, float4-streamed k row)
  float acc = 0.f;
  const float4* kr = reinterpret_cast<const float4*>(kf + creg * HD);
#pragma unroll
  for (int i = 0; i < 16; ++i) {
    float4 k4 = kr[i];
    acc += __shfl(qreg, 4 * i + 0) * k4.x;
    acc += __shfl(qreg, 4 * i + 1) * k4.y;
    acc += __shfl(qreg, 4 * i + 2) * k4.z;
    acc += __shfl(qreg, 4 * i + 3) * k4.w;
  }
  float e = (lane < d) ? __expf(acc * 0.125f) : 0.f;  // |s| O(1): no max-sub needed in fp32
  float s = e;
#pragma unroll
  for (int off = 1; off < 64; off <<= 1) s += __shfl_xor(s, off);
  float vreg = (s > 0.f) ? e / s : 0.f;               // normalized A row, slot = lane; 0 for lane>=d
  val[row * CAP + lane] = vreg;
  // hop1 (zin = vf): 8-deep gather
  float hacc = 0.f;
  GATHER8(hacc, vreg, creg, vf, d);
  zA[row * HD + lane] = 0.85f * hacc + 0.15f * vf[row * HD + lane];
}

// ---- K3/K4/K7/K8: split-wave sparse hop. TWO waves per row (interleaved slots 2e+half):
// each wave runs ~d/2 edges (2 GATHER8 batches instead of 4) and wave count doubles
// (6 waves/SIMD) -> half the serial latency chain, same total instructions.
__global__ __launch_bounds__(256) void k_hop(const float* __restrict__ val,
    const int* __restrict__ colb, const int* __restrict__ deg, const float* __restrict__ zin,
    const float* __restrict__ vf, float* __restrict__ zout) {
  __shared__ float part[2][HD];
  const int tid = threadIdx.x, lane = tid & 63, wave = tid >> 6;
  const int rloc = wave >> 1, half = wave & 1;
  const int row = blockIdx.x * 2 + rloc;
  const int d = deg[row];
  const int dh = (d + 1 - half) >> 1;          // count of slots 2e+half below d
  float vv = 0.f; int cc = 0;
  if (lane < 32) {                              // lane e holds slot 2e+half (<= 63)
    vv = val[row * CAP + 2 * lane + half];
    cc = colb[row * CAP + 2 * lane + half];
  }
  float acc = 0.f;
  GATHER8(acc, vv, cc, zin, dh);                // dh <= 32 -> shfl only touches lanes < 32
  if (half == 1) part[rloc][lane] = acc;
  __syncthreads();
  if (half == 0)
    zout[row * HD + lane] = 0.85f * (acc + part[rloc][lane]) + 0.15f * vf[row * HD + lane];
}

// ---- K5: hop4 + residual (h = emb + z) + qkv layer 2. Row-local via shfl.
__global__ __launch_bounds__(256) void k_hop_res_qkv(const float* __restrict__ val,
    const int* __restrict__ colb, const int* __restrict__ deg, const float* __restrict__ zin,
    const float* __restrict__ vf, const float* __restrict__ emb, float* __restrict__ hf,
    const float* __restrict__ Wq, const float* __restrict__ Wk, const float* __restrict__ Wv,
    float* __restrict__ qf, float* __restrict__ kf, float* __restrict__ vf2) {
  const int lane = threadIdx.x & 63;
  const int row = blockIdx.x * 4 + (threadIdx.x >> 6);
  const int d = deg[row];
  const float vreg = val[row * CAP + lane];
  const int creg = colb[row * CAP + lane];
  float acc = 0.f;
  GATHER8(acc, vreg, creg, zin, d);
  float z = 0.85f * acc + 0.15f * vf[row * HD + lane];
  float h = ((row < NC) ? emb[row * HD + lane] : 0.f) + z;
  hf[row * HD + lane] = h;
  float aq = 0.f, ak = 0.f, av = 0.f;
#pragma unroll 16
  for (int f = 0; f < HD; ++f) {
    float hv = __shfl(h, f);
    aq += hv * Wq[f * HD + lane];
    ak += hv * Wk[f * HD + lane];
    av += hv * Wv[f * HD + lane];
  }
  qf[row * HD + lane] = aq;
  kf[row * HD + lane] = ak;
  vf2[row * HD + lane] = av;
}

// ---- K9: hop4' + residual + cluster softmax + S/Wsum partials (LDS pre-reduced).
__global__ __launch_bounds__(1024) void k_hop_res_tail(const float* __restrict__ val,
    const int* __restrict__ colb, const int* __restrict__ deg, const float* __restrict__ zin,
    const float* __restrict__ vf, float* __restrict__ hf, const float* __restrict__ Wg,
    const float* __restrict__ bg, const float* __restrict__ Wp, float* __restrict__ s2,
    float* __restrict__ Sb) {
  __shared__ float Sl[NG * HD];
  __shared__ float Wl[16];
  const int tid = threadIdx.x, lane = tid & 63, wave = tid >> 6;
  const int row = blockIdx.x * 16 + wave;
  if (tid < NG * HD) Sl[tid] = 0.f;
  if (tid < 16) Wl[tid] = 0.f;
  __syncthreads();
  const int d = deg[row];
  const float vreg = val[row * CAP + lane];
  const int creg = colb[row * CAP + lane];
  float acc = 0.f;
  GATHER8(acc, vreg, creg, zin, d);
  float z = 0.85f * acc + 0.15f * vf[row * HD + lane];
  float h = hf[row * HD + lane] + z;
  hf[row * HD + lane] = h;
  if (row < NC) {
    float4 wg = *reinterpret_cast<const float4*>(Wg + lane * NG);
    float a0 = h * wg.x, a1 = h * wg.y, a2 = h * wg.z, a3 = h * wg.w;
#pragma unroll
    for (int off = 1; off < 64; off <<= 1) {
      a0 += __shfl_xor(a0, off); a1 += __shfl_xor(a1, off);
      a2 += __shfl_xor(a2, off); a3 += __shfl_xor(a3, off);
    }
    float lg0 = a0 + bg[0], lg1 = a1 + bg[1], lg2 = a2 + bg[2], lg3 = a3 + bg[3];
    float mx = fmaxf(fmaxf(lg0, lg1), fmaxf(lg2, lg3));
    float e0 = __expf(lg0 - mx), e1 = __expf(lg1 - mx), e2 = __expf(lg2 - mx), e3 = __expf(lg3 - mx);
    float inv = 1.f / (e0 + e1 + e2 + e3);
    float p0 = e0 * inv, p1 = e1 * inv, p2 = e2 * inv, p3 = e3 * inv;
    if (lane == 0) s2[row] = p0 * p0 + p1 * p1 + p2 * p2 + p3 * p3;
    float w = Wp[row];
    atomicAdd(&Sl[0 * HD + lane], p0 * w * h);
    atomicAdd(&Sl[1 * HD + lane], p1 * w * h);
    atomicAdd(&Sl[2 * HD + lane], p2 * w * h);
    atomicAdd(&Sl[3 * HD + lane], p3 * w * h);
    if (lane == 0) Wl[wave] = w;
  }
  __syncthreads();
  if (tid < NG * HD) atomicAdd(&Sb[tid], Sl[tid]);
  if (tid == 0) {
    float ws = 0.f;
#pragma unroll
    for (int i = 0; i < 16; ++i) ws += Wl[i];
    atomicAdd(&Sb[NG * HD], ws);
  }
}

// ---- K10: per-user closed-form BN + pool. 4 waves split the L-gather chain.
__global__ __launch_bounds__(256) void k_user(const int* __restrict__ cate, const float* __restrict__ hf,
    const float* __restrict__ s2, const float* __restrict__ Sb,
    const float* __restrict__ gamma, const float* __restrict__ beta, const float* __restrict__ bp,
    float* __restrict__ out) {
  const int b = blockIdx.x;
  const int tid = threadIdx.x, lane = tid & 63, wave = tid >> 6;
  __shared__ int cs[LQ];
  __shared__ float red[8][HD];
  if (tid < LQ) cs[tid] = cate[b * LQ + tid];
  __syncthreads();
  float msum = 0.f, qsum = 0.f;
#pragma unroll 4
  for (int l = wave; l < LQ; l += 4) {
    int c = cs[l];
    if (c != 0) {
      float gv = hf[c * HD + lane];
      msum += gv;
      qsum += s2[c] * gv * gv;
    }
  }
  red[wave][lane] = msum;
  red[4 + wave][lane] = qsum;
  __syncthreads();
  if (wave == 0) {
    msum = red[0][lane] + red[1][lane] + red[2][lane] + red[3][lane];
    qsum = red[4][lane] + red[5][lane] + red[6][lane] + red[7][lane];
    const float cntf = 1.f / (NG * LQ);
    float mean = msum * cntf;
    float var = fmaxf(qsum * cntf - mean * mean, 0.f);
    float inv = rsqrtf(var + 1e-5f);
    float gam = gamma[lane], bet = beta[lane], bpv = bp[0];
    float wsum = Sb[NG * HD];
#pragma unroll
    for (int g = 0; g < NG; ++g)
      out[b * (NG * HD) + g * HD + lane] = inv * gam * (Sb[g * HD + lane] - mean * wsum) + bet * wsum + bpv;
  }
}

extern "C" void kernel_launch(void* const* d_in, const int* in_sizes, int n_in,
                              void* d_out, int out_size, void* d_ws, size_t ws_size,
                              hipStream_t stream) {
  const int* cate = (const int*)d_in[0];
  const float* adj = (const float*)d_in[1];
  const float* emb = (const float*)d_in[2];
  const float* Wq = (const float*)d_in[3];
  const float* Wk = (const float*)d_in[4];
  const float* Wv = (const float*)d_in[5];
  const float* Wg = (const float*)d_in[6];
  const float* bg = (const float*)d_in[7];
  const float* Wp = (const float*)d_in[8];
  const float* bp = (const float*)d_in[9];
  const float* gamma = (const float*)d_in[10];
  const float* beta = (const float*)d_in[11];
  float* out = (float*)d_out;

  char* p = (char*)d_ws;
  auto carve = [&](size_t bytes) { char* r = p; p += (bytes + 255) & ~(size_t)255; return r; };
  float* hf = (float*)carve((size_t)NP * HD * 4);
  float* qf = (float*)carve((size_t)NP * HD * 4);
  float* kf = (float*)carve((size_t)NP * HD * 4);
  float* vf = (float*)carve((size_t)NP * HD * 4);
  float* vf2 = (float*)carve((size_t)NP * HD * 4);
  float* zA = (float*)carve((size_t)NP * HD * 4);
  float* zB = (float*)carve((size_t)NP * HD * 4);
  float* val = (float*)carve((size_t)NP * CAP * 4);
  int* colb = (int*)carve((size_t)NP * CAP * 4);
  int* deg  = (int*)carve((size_t)NP * 4);
  float* s2 = (float*)carve((size_t)NP * 4);
  float* Sb = (float*)carve((size_t)(NG * HD + 1) * 4);

  // layer 1
  k_pack_qkv<<<NP / 4, 256, 0, stream>>>(adj, emb, Wq, Wk, Wv, colb, deg, qf, kf, vf, Sb);
  k_score_hop<<<NP / 4, 256, 0, stream>>>(qf, kf, colb, deg, val, vf, zA);
  k_hop<<<NP / 2, 256, 0, stream>>>(val, colb, deg, zA, vf, zB);
  k_hop<<<NP / 2, 256, 0, stream>>>(val, colb, deg, zB, vf, zA);
  k_hop_res_qkv<<<NP / 4, 256, 0, stream>>>(val, colb, deg, zA, vf, emb, hf,
                                            Wq + HD * HD, Wk + HD * HD, Wv + HD * HD, qf, kf, vf2);
  // layer 2
  k_score_hop<<<NP / 4, 256, 0, stream>>>(qf, kf, colb, deg, val, vf2, zA);
  k_hop<<<NP / 2, 256, 0, stream>>>(val, colb, deg, zA, vf2, zB);
  k_hop<<<NP / 2, 256, 0, stream>>>(val, colb, deg, zB, vf2, zA);
  k_hop_res_tail<<<NP / 16, 1024, 0, stream>>>(val, colb, deg, zA, vf2, hf, Wg, bg, Wp, s2, Sb);
  k_user<<<NB, 256, 0, stream>>>(cate, hf, s2, Sb, gamma, beta, bp, out);
}

// Round 14
// 176.275 us; speedup vs baseline: 1.0446x; 1.0087x over previous
//
#include <hip/hip_runtime.h>
#include <hip/hip_bf16.h>

#define NC 3000   // num cates
#define NP 3072   // padded
#define CAP 64    // ELL slots per row (max degree ~52 at p=0.01; binom tail past 64 ~ 0)
#define HD 64
#define NG 4
#define LQ 50
#define NB 256
#define NQ4 750   // float4 words per adj row = NC/4

// 8-deep unrolled shfl-broadcast gather: A row lives in (vreg,creg) registers, slot = lane.
// Slots >= d hold (0, 0) so rounding d up to 8 adds exact-zero terms. dro <= 64 always.
// Measured optimum: GATHER64 (+9.2us), split-wave (+2.9us), coalesced-butterfly (+14.4us)
// all regress — these kernels are issue-bound; instruction count ~= cost.
#define GATHER8(acc, vreg, creg, zin, d)                                   \
  {                                                                        \
    int dro = ((d) + 7) & ~7;                                              \
    for (int e = 0; e < dro; e += 8) {                                     \
      float v0 = __shfl(vreg, e + 0), v1 = __shfl(vreg, e + 1);            \
      float v2 = __shfl(vreg, e + 2), v3 = __shfl(vreg, e + 3);            \
      float v4 = __shfl(vreg, e + 4), v5 = __shfl(vreg, e + 5);            \
      float v6 = __shfl(vreg, e + 6), v7 = __shfl(vreg, e + 7);            \
      int c0 = __shfl(creg, e + 0), c1 = __shfl(creg, e + 1);              \
      int c2 = __shfl(creg, e + 2), c3 = __shfl(creg, e + 3);              \
      int c4 = __shfl(creg, e + 4), c5 = __shfl(creg, e + 5);              \
      int c6 = __shfl(creg, e + 6), c7 = __shfl(creg, e + 7);              \
      float z0 = zin[c0 * HD + lane], z1 = zin[c1 * HD + lane];            \
      float z2 = zin[c2 * HD + lane], z3 = zin[c3 * HD + lane];            \
      float z4 = zin[c4 * HD + lane], z5 = zin[c5 * HD + lane];            \
      float z6 = zin[c6 * HD + lane], z7 = zin[c7 * HD + lane];            \
      acc += v0 * z0 + v1 * z1 + v2 * z2 + v3 * z3;                        \
      acc += v4 * z4 + v5 * z5 + v6 * z6 + v7 * z7;                        \
    }                                                                      \
  }

// ---- K1: pack adj -> ELL colb + deg (float4 + 4-ballot compaction), qkv layer 1, zero Sb.
__global__ __launch_bounds__(256) void k_pack_qkv(const float* __restrict__ adj,
    const float* __restrict__ emb, const float* __restrict__ Wq, const float* __restrict__ Wk,
    const float* __restrict__ Wv, int* __restrict__ colb, int* __restrict__ deg,
    float* __restrict__ qf, float* __restrict__ kf, float* __restrict__ vf,
    float* __restrict__ Sb) {
  const int tid = threadIdx.x, lane = tid & 63;
  const int row = blockIdx.x * 4 + (tid >> 6);
  if (blockIdx.x == 0) {           // fold in Sb zeroing (used only by K9, 8 dispatches later)
    if (tid < NG * HD) Sb[tid] = 0.f;
    if (tid == 0) Sb[NG * HD] = 0.f;
  }
  if (row < NC) {
    const float4* arow = reinterpret_cast<const float4*>(adj + (size_t)row * NC);  // 12000B: 16B-aligned
    const unsigned long long mlane = (1ull << lane) - 1ull;
    int base = 0;   // wave-uniform running edge count
#pragma unroll 3
    for (int g = 0; g < 12; ++g) {
      int idx = g * 64 + lane;     // float4 index; valid < NQ4
      float4 a4 = (idx < NQ4) ? arow[idx] : make_float4(0.f, 0.f, 0.f, 0.f);
      unsigned long long b0 = __ballot(a4.x != 0.f);
      unsigned long long b1 = __ballot(a4.y != 0.f);
      unsigned long long b2 = __ballot(a4.z != 0.f);
      unsigned long long b3 = __ballot(a4.w != 0.f);
      if (a4.x != 0.f) { int s = base + __popcll(b0 & mlane); if (s < CAP) colb[row * CAP + s] = 4 * idx + 0; }
      base += __popcll(b0);
      if (a4.y != 0.f) { int s = base + __popcll(b1 & mlane); if (s < CAP) colb[row * CAP + s] = 4 * idx + 1; }
      base += __popcll(b1);
      if (a4.z != 0.f) { int s = base + __popcll(b2 & mlane); if (s < CAP) colb[row * CAP + s] = 4 * idx + 2; }
      base += __popcll(b2);
      if (a4.w != 0.f) { int s = base + __popcll(b3 & mlane); if (s < CAP) colb[row * CAP + s] = 4 * idx + 3; }
      base += __popcll(b3);
    }
    int d = (base < CAP) ? base : CAP;
    if (lane == 0) deg[row] = d;
    if (lane >= d) colb[row * CAP + lane] = 0;   // zero-fill tail (val tail will be 0)
    // qkv: lane = output col; h row broadcast via shfl
    float hreg = emb[row * HD + lane];
    float aq = 0.f, ak = 0.f, av = 0.f;
#pragma unroll 16
    for (int f = 0; f < HD; ++f) {
      float hv = __shfl(hreg, f);
      aq += hv * Wq[f * HD + lane];
      ak += hv * Wk[f * HD + lane];
      av += hv * Wv[f * HD + lane];
    }
    qf[row * HD + lane] = aq;
    kf[row * HD + lane] = ak;
    vf[row * HD + lane] = av;
  } else {
    if (lane == 0) deg[row] = 0;
    colb[row * CAP + lane] = 0;
    qf[row * HD + lane] = 0.f;
    kf[row * HD + lane] = 0.f;
    vf[row * HD + lane] = 0.f;
  }
}

// ---- K2/K6: edge-wise scores + softmax + hop1. Wave per row; lane = edge slot.
__global__ __launch_bounds__(256) void k_score_hop(const float* __restrict__ qf,
    const float* __restrict__ kf, const int* __restrict__ colb, const int* __restrict__ deg,
    float* __restrict__ val, const float* __restrict__ vf, float* __restrict__ zA) {
  const int tid = threadIdx.x, lane = tid & 63;
  const int row = blockIdx.x * 4 + (tid >> 6);
  const int d = deg[row];
  const int creg = colb[row * CAP + lane];
  const float qreg = qf[row * HD + lane];   // lane f holds q[row][f]
  // lane e: s_e = q_row . k_{c_e}  (fp32, float4-streamed k row)
  float acc = 0.f;
  const float4* kr = reinterpret_cast<const float4*>(kf + creg * HD);
#pragma unroll
  for (int i = 0; i < 16; ++i) {
    float4 k4 = kr[i];
    acc += __shfl(qreg, 4 * i + 0) * k4.x;
    acc += __shfl(qreg, 4 * i + 1) * k4.y;
    acc += __shfl(qreg, 4 * i + 2) * k4.z;
    acc += __shfl(qreg, 4 * i + 3) * k4.w;
  }
  float e = (lane < d) ? __expf(acc * 0.125f) : 0.f;  // |s| O(1): no max-sub needed in fp32
  float s = e;
#pragma unroll
  for (int off = 1; off < 64; off <<= 1) s += __shfl_xor(s, off);
  float vreg = (s > 0.f) ? e / s : 0.f;               // normalized A row, slot = lane; 0 for lane>=d
  val[row * CAP + lane] = vreg;
  // hop1 (zin = vf): 8-deep gather
  float hacc = 0.f;
  GATHER8(hacc, vreg, creg, vf, d);
  zA[row * HD + lane] = 0.85f * hacc + 0.15f * vf[row * HD + lane];
}

// ---- K3/K4/K7/K8: plain sparse hop. Wave per row; A row in registers, 8-deep gathers.
__global__ __launch_bounds__(256) void k_hop(const float* __restrict__ val,
    const int* __restrict__ colb, const int* __restrict__ deg, const float* __restrict__ zin,
    const float* __restrict__ vf, float* __restrict__ zout) {
  const int lane = threadIdx.x & 63;
  const int row = blockIdx.x * 4 + (threadIdx.x >> 6);
  const int d = deg[row];
  const float vreg = val[row * CAP + lane];
  const int creg = colb[row * CAP + lane];
  float acc = 0.f;
  GATHER8(acc, vreg, creg, zin, d);
  zout[row * HD + lane] = 0.85f * acc + 0.15f * vf[row * HD + lane];
}

// ---- K5: hop4 + residual (h = emb + z) + qkv layer 2. Row-local via shfl.
__global__ __launch_bounds__(256) void k_hop_res_qkv(const float* __restrict__ val,
    const int* __restrict__ colb, const int* __restrict__ deg, const float* __restrict__ zin,
    const float* __restrict__ vf, const float* __restrict__ emb, float* __restrict__ hf,
    const float* __restrict__ Wq, const float* __restrict__ Wk, const float* __restrict__ Wv,
    float* __restrict__ qf, float* __restrict__ kf, float* __restrict__ vf2) {
  const int lane = threadIdx.x & 63;
  const int row = blockIdx.x * 4 + (threadIdx.x >> 6);
  const int d = deg[row];
  const float vreg = val[row * CAP + lane];
  const int creg = colb[row * CAP + lane];
  float acc = 0.f;
  GATHER8(acc, vreg, creg, zin, d);
  float z = 0.85f * acc + 0.15f * vf[row * HD + lane];
  float h = ((row < NC) ? emb[row * HD + lane] : 0.f) + z;
  hf[row * HD + lane] = h;
  float aq = 0.f, ak = 0.f, av = 0.f;
#pragma unroll 16
  for (int f = 0; f < HD; ++f) {
    float hv = __shfl(h, f);
    aq += hv * Wq[f * HD + lane];
    ak += hv * Wk[f * HD + lane];
    av += hv * Wv[f * HD + lane];
  }
  qf[row * HD + lane] = aq;
  kf[row * HD + lane] = ak;
  vf2[row * HD + lane] = av;
}

// ---- K9: hop4' + residual + cluster softmax + S/Wsum partials (LDS pre-reduced).
__global__ __launch_bounds__(1024) void k_hop_res_tail(const float* __restrict__ val,
    const int* __restrict__ colb, const int* __restrict__ deg, const float* __restrict__ zin,
    const float* __restrict__ vf, float* __restrict__ hf, const float* __restrict__ Wg,
    const float* __restrict__ bg, const float* __restrict__ Wp, float* __restrict__ s2,
    float* __restrict__ Sb) {
  __shared__ float Sl[NG * HD];
  __shared__ float Wl[16];
  const int tid = threadIdx.x, lane = tid & 63, wave = tid >> 6;
  const int row = blockIdx.x * 16 + wave;
  if (tid < NG * HD) Sl[tid] = 0.f;
  if (tid < 16) Wl[tid] = 0.f;
  __syncthreads();
  const int d = deg[row];
  const float vreg = val[row * CAP + lane];
  const int creg = colb[row * CAP + lane];
  float acc = 0.f;
  GATHER8(acc, vreg, creg, zin, d);
  float z = 0.85f * acc + 0.15f * vf[row * HD + lane];
  float h = hf[row * HD + lane] + z;
  hf[row * HD + lane] = h;
  if (row < NC) {
    float4 wg = *reinterpret_cast<const float4*>(Wg + lane * NG);
    float a0 = h * wg.x, a1 = h * wg.y, a2 = h * wg.z, a3 = h * wg.w;
#pragma unroll
    for (int off = 1; off < 64; off <<= 1) {
      a0 += __shfl_xor(a0, off); a1 += __shfl_xor(a1, off);
      a2 += __shfl_xor(a2, off); a3 += __shfl_xor(a3, off);
    }
    float lg0 = a0 + bg[0], lg1 = a1 + bg[1], lg2 = a2 + bg[2], lg3 = a3 + bg[3];
    float mx = fmaxf(fmaxf(lg0, lg1), fmaxf(lg2, lg3));
    float e0 = __expf(lg0 - mx), e1 = __expf(lg1 - mx), e2 = __expf(lg2 - mx), e3 = __expf(lg3 - mx);
    float inv = 1.f / (e0 + e1 + e2 + e3);
    float p0 = e0 * inv, p1 = e1 * inv, p2 = e2 * inv, p3 = e3 * inv;
    if (lane == 0) s2[row] = p0 * p0 + p1 * p1 + p2 * p2 + p3 * p3;
    float w = Wp[row];
    atomicAdd(&Sl[0 * HD + lane], p0 * w * h);
    atomicAdd(&Sl[1 * HD + lane], p1 * w * h);
    atomicAdd(&Sl[2 * HD + lane], p2 * w * h);
    atomicAdd(&Sl[3 * HD + lane], p3 * w * h);
    if (lane == 0) Wl[wave] = w;
  }
  __syncthreads();
  if (tid < NG * HD) atomicAdd(&Sb[tid], Sl[tid]);
  if (tid == 0) {
    float ws = 0.f;
#pragma unroll
    for (int i = 0; i < 16; ++i) ws += Wl[i];
    atomicAdd(&Sb[NG * HD], ws);
  }
}

// ---- K10: per-user closed-form BN + pool. 4 waves split the L-gather chain.
__global__ __launch_bounds__(256) void k_user(const int* __restrict__ cate, const float* __restrict__ hf,
    const float* __restrict__ s2, const float* __restrict__ Sb,
    const float* __restrict__ gamma, const float* __restrict__ beta, const float* __restrict__ bp,
    float* __restrict__ out) {
  const int b = blockIdx.x;
  const int tid = threadIdx.x, lane = tid & 63, wave = tid >> 6;
  __shared__ int cs[LQ];
  __shared__ float red[8][HD];
  if (tid < LQ) cs[tid] = cate[b * LQ + tid];
  __syncthreads();
  float msum = 0.f, qsum = 0.f;
#pragma unroll 4
  for (int l = wave; l < LQ; l += 4) {
    int c = cs[l];
    if (c != 0) {
      float gv = hf[c * HD + lane];
      msum += gv;
      qsum += s2[c] * gv * gv;
    }
  }
  red[wave][lane] = msum;
  red[4 + wave][lane] = qsum;
  __syncthreads();
  if (wave == 0) {
    msum = red[0][lane] + red[1][lane] + red[2][lane] + red[3][lane];
    qsum = red[4][lane] + red[5][lane] + red[6][lane] + red[7][lane];
    const float cntf = 1.f / (NG * LQ);
    float mean = msum * cntf;
    float var = fmaxf(qsum * cntf - mean * mean, 0.f);
    float inv = rsqrtf(var + 1e-5f);
    float gam = gamma[lane], bet = beta[lane], bpv = bp[0];
    float wsum = Sb[NG * HD];
#pragma unroll
    for (int g = 0; g < NG; ++g)
      out[b * (NG * HD) + g * HD + lane] = inv * gam * (Sb[g * HD + lane] - mean * wsum) + bet * wsum + bpv;
  }
}

extern "C" void kernel_launch(void* const* d_in, const int* in_sizes, int n_in,
                              void* d_out, int out_size, void* d_ws, size_t ws_size,
                              hipStream_t stream) {
  const int* cate = (const int*)d_in[0];
  const float* adj = (const float*)d_in[1];
  const float* emb = (const float*)d_in[2];
  const float* Wq = (const float*)d_in[3];
  const float* Wk = (const float*)d_in[4];
  const float* Wv = (const float*)d_in[5];
  const float* Wg = (const float*)d_in[6];
  const float* bg = (const float*)d_in[7];
  const float* Wp = (const float*)d_in[8];
  const float* bp = (const float*)d_in[9];
  const float* gamma = (const float*)d_in[10];
  const float* beta = (const float*)d_in[11];
  float* out = (float*)d_out;

  char* p = (char*)d_ws;
  auto carve = [&](size_t bytes) { char* r = p; p += (bytes + 255) & ~(size_t)255; return r; };
  float* hf = (float*)carve((size_t)NP * HD * 4);
  float* qf = (float*)carve((size_t)NP * HD * 4);
  float* kf = (float*)carve((size_t)NP * HD * 4);
  float* vf = (float*)carve((size_t)NP * HD * 4);
  float* vf2 = (float*)carve((size_t)NP * HD * 4);
  float* zA = (float*)carve((size_t)NP * HD * 4);
  float* zB = (float*)carve((size_t)NP * HD * 4);
  float* val = (float*)carve((size_t)NP * CAP * 4);
  int* colb = (int*)carve((size_t)NP * CAP * 4);
  int* deg  = (int*)carve((size_t)NP * 4);
  float* s2 = (float*)carve((size_t)NP * 4);
  float* Sb = (float*)carve((size_t)(NG * HD + 1) * 4);

  // layer 1
  k_pack_qkv<<<NP / 4, 256, 0, stream>>>(adj, emb, Wq, Wk, Wv, colb, deg, qf, kf, vf, Sb);
  k_score_hop<<<NP / 4, 256, 0, stream>>>(qf, kf, colb, deg, val, vf, zA);
  k_hop<<<NP / 4, 256, 0, stream>>>(val, colb, deg, zA, vf, zB);
  k_hop<<<NP / 4, 256, 0, stream>>>(val, colb, deg, zB, vf, zA);
  k_hop_res_qkv<<<NP / 4, 256, 0, stream>>>(val, colb, deg, zA, vf, emb, hf,
                                            Wq + HD * HD, Wk + HD * HD, Wv + HD * HD, qf, kf, vf2);
  // layer 2
  k_score_hop<<<NP / 4, 256, 0, stream>>>(qf, kf, colb, deg, val, vf2, zA);
  k_hop<<<NP / 4, 256, 0, stream>>>(val, colb, deg, zA, vf2, zB);
  k_hop<<<NP / 4, 256, 0, stream>>>(val, colb, deg, zB, vf2, zA);
  k_hop_res_tail<<<NP / 16, 1024, 0, stream>>>(val, colb, deg, zA, vf2, hf, Wg, bg, Wp, s2, Sb);
  k_user<<<NB, 256, 0, stream>>>(cate, hf, s2, Sb, gamma, beta, bp, out);
}